// Round 1
// baseline (419.717 us; speedup 1.0000x reference)
//
#include <hip/hip_runtime.h>
#include <hip/hip_bf16.h>

// RMSNorm + dynamic per-token int8 quant.
// x: [R=16384, H=4096] fp32, w: [H] fp32.
// out: first R*H floats = quantized values (as fp32), next R floats = scales.
//
// Trick: q = round(normed/scale) = round(x*w * 127 / max|x*w|) -- rstd cancels,
// so both reductions (sum x^2, max|x*w|) happen in ONE pass; the row stays in
// registers (16 floats/thread), giving read-once / write-once HBM traffic.

constexpr int H = 4096;
constexpr int BLOCK = 256;
constexpr int VPT = H / (BLOCK * 4); // 4 float4 per thread

__global__ __launch_bounds__(BLOCK)
void qrmsnorm_kernel(const float* __restrict__ x, const float* __restrict__ w,
                     float* __restrict__ out, float* __restrict__ scale_out) {
    const int row = blockIdx.x;
    const long long base = (long long)row * H;
    const float4* __restrict__ xv = (const float4*)(x + base);
    const float4* __restrict__ wv = (const float4*)w;

    float4 xw[VPT];
    float ss = 0.0f;   // sum of squares of x
    float am = 0.0f;   // max |x*w|

#pragma unroll
    for (int j = 0; j < VPT; ++j) {
        const int idx = j * BLOCK + threadIdx.x;      // coalesced: 16B/lane
        float4 xx = xv[idx];
        float4 ww = wv[idx];
        ss = fmaf(xx.x, xx.x, ss);
        ss = fmaf(xx.y, xx.y, ss);
        ss = fmaf(xx.z, xx.z, ss);
        ss = fmaf(xx.w, xx.w, ss);
        float4 p;
        p.x = xx.x * ww.x; p.y = xx.y * ww.y;
        p.z = xx.z * ww.z; p.w = xx.w * ww.w;
        am = fmaxf(am, fmaxf(fmaxf(fabsf(p.x), fabsf(p.y)),
                             fmaxf(fabsf(p.z), fabsf(p.w))));
        xw[j] = p;
    }

    // wave(64)-level reduction
#pragma unroll
    for (int off = 32; off > 0; off >>= 1) {
        ss += __shfl_down(ss, off);
        am = fmaxf(am, __shfl_down(am, off));
    }

    __shared__ float s_ss[BLOCK / 64];
    __shared__ float s_am[BLOCK / 64];
    const int wave = threadIdx.x >> 6;
    const int lane = threadIdx.x & 63;
    if (lane == 0) { s_ss[wave] = ss; s_am[wave] = am; }
    __syncthreads();

    const float tss = s_ss[0] + s_ss[1] + s_ss[2] + s_ss[3];
    const float tam = fmaxf(fmaxf(s_am[0], s_am[1]), fmaxf(s_am[2], s_am[3]));

    const float rstd = rsqrtf(tss * (1.0f / (float)H) + 1e-6f);
    const float inv = (tam > 0.0f) ? (127.0f / tam) : 0.0f;

    float4* __restrict__ ov = (float4*)(out + base);
#pragma unroll
    for (int j = 0; j < VPT; ++j) {
        const int idx = j * BLOCK + threadIdx.x;
        float4 p = xw[j];
        float4 q;
        q.x = fminf(fmaxf(rintf(p.x * inv), -128.0f), 127.0f);
        q.y = fminf(fmaxf(rintf(p.y * inv), -128.0f), 127.0f);
        q.z = fminf(fmaxf(rintf(p.z * inv), -128.0f), 127.0f);
        q.w = fminf(fmaxf(rintf(p.w * inv), -128.0f), 127.0f);
        ov[idx] = q;
    }

    if (threadIdx.x == 0) {
        scale_out[row] = tam * rstd * (1.0f / 127.0f);
    }
}

extern "C" void kernel_launch(void* const* d_in, const int* in_sizes, int n_in,
                              void* d_out, int out_size, void* d_ws, size_t ws_size,
                              hipStream_t stream) {
    const float* x = (const float*)d_in[0];
    const float* w = (const float*)d_in[1];
    float* out = (float*)d_out;

    const int h = in_sizes[1];            // 4096
    const int rows = in_sizes[0] / h;     // 16384
    float* scale_out = out + (long long)rows * h;

    qrmsnorm_kernel<<<rows, BLOCK, 0, stream>>>(x, w, out, scale_out);
}

// Round 3
// 415.108 us; speedup vs baseline: 1.0111x; 1.0111x over previous
//
#include <hip/hip_runtime.h>
#include <hip/hip_bf16.h>

// RMSNorm + dynamic per-token int8 quant.
// x: [R=16384, H=4096] fp32, w: [H] fp32.
// out: first R*H floats = quantized values (as fp32), next R floats = scales.
//
// q = round(x*w * 127 / max|x*w|) -- rstd cancels, so sum(x^2) and max|x*w|
// are computed in ONE pass with the row held in registers.
// R3: same as R2 but with clang ext_vector_type for the nontemporal builtins
// (HIP float4 is a struct; the builtin requires a true vector type).

constexpr int H = 4096;
constexpr int BLOCK = 256;
constexpr int VPT = H / (BLOCK * 4); // 4 vec4 per thread per row

typedef float fx4 __attribute__((ext_vector_type(4)));

__global__ __launch_bounds__(BLOCK)
void qrmsnorm_kernel(const float* __restrict__ x, const float* __restrict__ w,
                     float* __restrict__ out, float* __restrict__ scale_out) {
    const int row0 = blockIdx.x * 2;
    const int row1 = row0 + 1;
    const fx4* __restrict__ xv0 = (const fx4*)(x + (long long)row0 * H);
    const fx4* __restrict__ xv1 = (const fx4*)(x + (long long)row1 * H);
    const fx4* __restrict__ wv = (const fx4*)w;

    fx4 ww[VPT], p0[VPT], p1[VPT];
    float ss0 = 0.0f, am0 = 0.0f, ss1 = 0.0f, am1 = 0.0f;

    // Issue all streaming loads up front: 8 independent nt 16B loads/thread.
#pragma unroll
    for (int j = 0; j < VPT; ++j) {
        const int idx = j * BLOCK + threadIdx.x;   // coalesced, 16B/lane
        p0[j] = __builtin_nontemporal_load(&xv0[idx]);
        p1[j] = __builtin_nontemporal_load(&xv1[idx]);
        ww[j] = wv[idx];                            // cached (reused chip-wide)
    }

#pragma unroll
    for (int j = 0; j < VPT; ++j) {
        fx4 a = p0[j], b = p1[j], c = ww[j];
        ss0 = fmaf(a.x, a.x, ss0); ss0 = fmaf(a.y, a.y, ss0);
        ss0 = fmaf(a.z, a.z, ss0); ss0 = fmaf(a.w, a.w, ss0);
        ss1 = fmaf(b.x, b.x, ss1); ss1 = fmaf(b.y, b.y, ss1);
        ss1 = fmaf(b.z, b.z, ss1); ss1 = fmaf(b.w, b.w, ss1);
        a *= c;
        b *= c;
        am0 = fmaxf(am0, fmaxf(fmaxf(fabsf(a.x), fabsf(a.y)),
                               fmaxf(fabsf(a.z), fabsf(a.w))));
        am1 = fmaxf(am1, fmaxf(fmaxf(fabsf(b.x), fabsf(b.y)),
                               fmaxf(fabsf(b.z), fabsf(b.w))));
        p0[j] = a; p1[j] = b;
    }

    // wave(64) butterfly reduction for both rows
#pragma unroll
    for (int off = 32; off > 0; off >>= 1) {
        ss0 += __shfl_xor(ss0, off);
        ss1 += __shfl_xor(ss1, off);
        am0 = fmaxf(am0, __shfl_xor(am0, off));
        am1 = fmaxf(am1, __shfl_xor(am1, off));
    }

    __shared__ float s_red[4][4];  // [wave][ss0, am0, ss1, am1]
    const int wave = threadIdx.x >> 6;
    if ((threadIdx.x & 63) == 0) {
        s_red[wave][0] = ss0; s_red[wave][1] = am0;
        s_red[wave][2] = ss1; s_red[wave][3] = am1;
    }
    __syncthreads();

    const float tss0 = s_red[0][0] + s_red[1][0] + s_red[2][0] + s_red[3][0];
    const float tam0 = fmaxf(fmaxf(s_red[0][1], s_red[1][1]),
                             fmaxf(s_red[2][1], s_red[3][1]));
    const float tss1 = s_red[0][2] + s_red[1][2] + s_red[2][2] + s_red[3][2];
    const float tam1 = fmaxf(fmaxf(s_red[0][3], s_red[1][3]),
                             fmaxf(s_red[2][3], s_red[3][3]));

    const float inv0 = (tam0 > 0.0f) ? (127.0f / tam0) : 0.0f;
    const float inv1 = (tam1 > 0.0f) ? (127.0f / tam1) : 0.0f;

    fx4* __restrict__ ov0 = (fx4*)(out + (long long)row0 * H);
    fx4* __restrict__ ov1 = (fx4*)(out + (long long)row1 * H);
#pragma unroll
    for (int j = 0; j < VPT; ++j) {
        const int idx = j * BLOCK + threadIdx.x;
        fx4 a = p0[j], b = p1[j], q;
        q.x = fminf(fmaxf(rintf(a.x * inv0), -128.0f), 127.0f);
        q.y = fminf(fmaxf(rintf(a.y * inv0), -128.0f), 127.0f);
        q.z = fminf(fmaxf(rintf(a.z * inv0), -128.0f), 127.0f);
        q.w = fminf(fmaxf(rintf(a.w * inv0), -128.0f), 127.0f);
        __builtin_nontemporal_store(q, &ov0[idx]);
        q.x = fminf(fmaxf(rintf(b.x * inv1), -128.0f), 127.0f);
        q.y = fminf(fmaxf(rintf(b.y * inv1), -128.0f), 127.0f);
        q.z = fminf(fmaxf(rintf(b.z * inv1), -128.0f), 127.0f);
        q.w = fminf(fmaxf(rintf(b.w * inv1), -128.0f), 127.0f);
        __builtin_nontemporal_store(q, &ov1[idx]);
    }

    if (threadIdx.x == 0) {
        const float rstd0 = rsqrtf(tss0 * (1.0f / (float)H) + 1e-6f);
        const float rstd1 = rsqrtf(tss1 * (1.0f / (float)H) + 1e-6f);
        scale_out[row0] = tam0 * rstd0 * (1.0f / 127.0f);
        scale_out[row1] = tam1 * rstd1 * (1.0f / 127.0f);
    }
}

extern "C" void kernel_launch(void* const* d_in, const int* in_sizes, int n_in,
                              void* d_out, int out_size, void* d_ws, size_t ws_size,
                              hipStream_t stream) {
    const float* x = (const float*)d_in[0];
    const float* w = (const float*)d_in[1];
    float* out = (float*)d_out;

    const int h = in_sizes[1];            // 4096
    const int rows = in_sizes[0] / h;     // 16384
    float* scale_out = out + (long long)rows * h;

    qrmsnorm_kernel<<<rows / 2, BLOCK, 0, stream>>>(x, w, out, scale_out);
}